// Round 11
// baseline (234322.705 us; speedup 1.0000x reference)
//
#include <hip/hip_runtime.h>

// ---- problem dims ----
#define T_DIM 256
#define NCOL 4608   // 3 gates * NB * BS  (col index n = g*1536 + k*256 + h)
// persistent grid: 144 gi blocks (32 cols each, wi hi+lo slices in LDS)
//                 + 64 B blocks (Phase B + LOCAL gh GEMV; no LDS weight slice)
#define GRID_N 208
#define GBUF 294912u   // floats per gi_raw buffer (64*4608); 4-deep ring

typedef __bf16 bf16x8 __attribute__((ext_vector_type(8)));
typedef float f32x4 __attribute__((ext_vector_type(4)));

#define MFMA16(a, b, c) __builtin_amdgcn_mfma_f32_16x16x32_bf16((a), (b), (c), 0, 0, 0)

#define CLOAD_F(ptr) __hip_atomic_load((ptr), __ATOMIC_RELAXED, __HIP_MEMORY_SCOPE_AGENT)
#define CSTORE_F(ptr, v) __hip_atomic_store((ptr), (v), __ATOMIC_RELAXED, __HIP_MEMORY_SCOPE_AGENT)

__device__ __forceinline__ unsigned short f2bf(float f) {
  unsigned u = __float_as_uint(f);
  unsigned r = u + 0x7FFFu + ((u >> 16) & 1u);
  return (unsigned short)(r >> 16);
}
__device__ __forceinline__ float bf2f(unsigned short s) {
  return __uint_as_float(((unsigned)s) << 16);
}
// split-bf16: x ~= hi + lo with |x - hi - lo| <= 2^-18 |x|
__device__ __forceinline__ void split2(float f, unsigned short* hi, unsigned short* lo) {
  unsigned short h = f2bf(f);
  *hi = h;
  *lo = f2bf(f - bf2f(h));
}

__device__ __forceinline__ void pack8_split(const float* p, bf16x8* hi, bf16x8* lo) {
  union { unsigned short s[8]; bf16x8 v; } uh, ul;
#pragma unroll
  for (int i = 0; i < 8; ++i) split2(p[i], &uh.s[i], &ul.s[i]);
  *hi = uh.v;
  *lo = ul.v;
}

__device__ __forceinline__ float sigm(float x) { return 1.f / (1.f + expf(-x)); }

// ================= precompute kernels =================

// weight transposes to split-bf16 hi/lo planes (wv, wi used; wh planes written but
// unused by the local-gh design -- kept to minimize diff vs verified kernel)
__global__ void convert_weights(const float* __restrict__ wv, const float* __restrict__ wi,
                                const float* __restrict__ wh,
                                unsigned short* __restrict__ wv_hi, unsigned short* __restrict__ wv_lo,
                                unsigned short* __restrict__ wi_hi, unsigned short* __restrict__ wi_lo,
                                unsigned short* __restrict__ wh_hi, unsigned short* __restrict__ wh_lo) {
  const size_t N0 = 1024u * 1536u;
  const size_t N1 = 18u * 256u * 1024u;
  const size_t N2 = 18u * 256u * 256u;
  for (size_t idx = blockIdx.x * 256u + threadIdx.x; idx < N0 + N1 + N2;
       idx += (size_t)gridDim.x * 256u) {
    if (idx < N0) {
      size_t n = idx / 1536u, kk = idx % 1536u;
      split2(wv[kk * 1024u + n], &wv_hi[idx], &wv_lo[idx]);
    } else if (idx < N0 + N1) {
      size_t r = idx - N0;
      size_t gk = r / 262144u, rem = r % 262144u;
      size_t h = rem / 1024u, kk = rem % 1024u;
      split2(wi[gk * 262144u + kk * 256u + h], &wi_hi[r], &wi_lo[r]);
    } else {
      size_t r = idx - N0 - N1;
      size_t gk = r / 65536u, rem = r % 65536u;
      size_t nout = rem / 256u, kin = rem % 256u;
      split2(wh[gk * 65536u + kin * 256u + nout], &wh_hi[r], &wh_lo[r]);
    }
  }
}

// fp32 transposes of the small comm-attn weights (vector-load-friendly rows);
// FP summation order in consumers is unchanged (j stays sequential).
__global__ void transpose_small(const float* __restrict__ cq, const float* __restrict__ ck,
                                const float* __restrict__ cv, const float* __restrict__ wq,
                                const float* __restrict__ cfc,
                                float* __restrict__ cqT, float* __restrict__ ckT,
                                float* __restrict__ cvT, float* __restrict__ wqT,
                                float* __restrict__ cfcT) {
  int i = blockIdx.x * 256 + threadIdx.x;
  if (i < 16384) {            // [256][64] -> [64][256]
    int r = i >> 6, c = i & 63;
    cqT[c * 256 + r] = cq[i];
    ckT[c * 256 + r] = ck[i];
    cvT[c * 256 + r] = cv[i];
    wqT[c * 256 + r] = wq[i];
  } else if (i < 32768) {     // cfc [64][256] -> [256][64]
    int j = i - 16384;
    int r = j >> 8, c = j & 255;
    cfcT[c * 64 + r] = cfc[j];
  }
}

// kx[t*64+b][64] = x @ wk + bk  -- exact fp32 (feeds discrete top-k decisions)
__global__ void kx_kernel(const float* __restrict__ x, const float* __restrict__ wk,
                          const float* __restrict__ bk, float* __restrict__ kx) {
  __shared__ float xs[16][64];
  const int mb = blockIdx.x;
  const int tid = threadIdx.x;
  const int mi = tid >> 6, n = tid & 63;
  float acc[4] = {0.f, 0.f, 0.f, 0.f};
  for (int kk0 = 0; kk0 < 1536; kk0 += 64) {
    __syncthreads();
    for (int i = tid; i < 1024; i += 256) {
      int r = i >> 6, c = i & 63;
      xs[r][c] = x[(size_t)(mb * 16 + r) * 1536u + kk0 + c];
    }
    __syncthreads();
    for (int c = 0; c < 64; ++c) {
      float w = wk[(size_t)(kk0 + c) * 64u + n];
      acc[0] += xs[mi][c] * w;
      acc[1] += xs[mi + 4][c] * w;
      acc[2] += xs[mi + 8][c] * w;
      acc[3] += xs[mi + 12][c] * w;
    }
  }
  for (int i = 0; i < 4; ++i)
    kx[(size_t)(mb * 16 + mi + 4 * i) * 64u + n] = acc[i] + bk[n];
}

// xv = x @ wv + bv via split-bf16 MFMA (3-term), output stored as hi/lo planes
__global__ __launch_bounds__(256) void xv_gemm(const float* __restrict__ x,
                                               const unsigned short* __restrict__ wv_hi,
                                               const unsigned short* __restrict__ wv_lo,
                                               const float* __restrict__ bv,
                                               unsigned short* __restrict__ xv_hi,
                                               unsigned short* __restrict__ xv_lo) {
  const int nb = blockIdx.x, mb = blockIdx.y;  // 8 x 128
  const int tid = threadIdx.x;
  const int w = tid >> 6, lane = tid & 63;
  const int mh = w >> 1, nh = w & 1;
  const int row = lane & 15, q8 = (lane >> 4) * 8;
  const int m0 = mb * 128 + mh * 64;
  const int n0 = nb * 128 + nh * 64;
  f32x4 acc[4][4];
#pragma unroll
  for (int i = 0; i < 4; ++i)
#pragma unroll
    for (int j = 0; j < 4; ++j) acc[i][j] = (f32x4){0.f, 0.f, 0.f, 0.f};
  for (int kk = 0; kk < 1536; kk += 32) {
    bf16x8 ah[4], al[4], bh[4], bl[4];
#pragma unroll
    for (int mt = 0; mt < 4; ++mt)
      pack8_split(x + (size_t)(m0 + mt * 16 + row) * 1536u + kk + q8, &ah[mt], &al[mt]);
#pragma unroll
    for (int nt = 0; nt < 4; ++nt) {
      size_t off = (size_t)(n0 + nt * 16 + row) * 1536u + kk + q8;
      bh[nt] = *(const bf16x8*)(wv_hi + off);
      bl[nt] = *(const bf16x8*)(wv_lo + off);
    }
#pragma unroll
    for (int mt = 0; mt < 4; ++mt)
#pragma unroll
      for (int nt = 0; nt < 4; ++nt) {
        acc[mt][nt] = MFMA16(ah[mt], bh[nt], acc[mt][nt]);
        acc[mt][nt] = MFMA16(al[mt], bh[nt], acc[mt][nt]);
        acc[mt][nt] = MFMA16(ah[mt], bl[nt], acc[mt][nt]);
      }
  }
  const int quad = lane >> 4, col = lane & 15;
#pragma unroll
  for (int mt = 0; mt < 4; ++mt)
#pragma unroll
    for (int nt = 0; nt < 4; ++nt)
#pragma unroll
      for (int r = 0; r < 4; ++r) {
        int m = m0 + mt * 16 + quad * 4 + r;
        int n = n0 + nt * 16 + col;
        split2(acc[mt][nt][r] + bv[n], &xv_hi[(size_t)m * 1024u + n],
               &xv_lo[(size_t)m * 1024u + n]);
      }
}

// c0[gk][h] = bv @ wi[gk]   (null-slot value path; exact fp32)
__global__ void c0_kernel(const float* __restrict__ bv, const float* __restrict__ wi,
                          float* __restrict__ c0) {
  const int gk = blockIdx.x, h = threadIdx.x;
  const float* wp = wi + (size_t)gk * 262144u + h;
  float acc = 0.f;
  for (int kk = 0; kk < 1024; ++kk) acc += bv[kk] * wp[(size_t)kk * 256u];
  c0[gk * 256 + h] = acc;
}

// ================= persistent kernel =================

struct KParams {
  const float *h_in, *wq, *bq, *bk;
  const float *bi, *bh, *wh;            // wh: raw fp32, streamed by B blocks (L2/L3-hot)
  const float *cq, *cbq, *ck, *cbk, *cv, *cbv, *cfc, *cbfc, *ln_g, *ln_b;
  const float *cqT, *ckT, *cvT, *wqT, *cfcT;
  const unsigned short *xv_hi, *xv_lo, *wi_hi, *wi_lo;
  const float *kx, *c0;
  float* gi_raw;              // 4-deep ring (t&3), device-coherent
  unsigned* bar;              // PER-SLOT counter groups (see below)
  float* out;
};

// Phase-B scratch (B blocks): placed at smem+65536 (same layout as verified r8).
struct PhaseB {
  float hs[6][256], hx[6][256];
  float qv[6][64];
  float q2s[6][64], k2s[6][64], v2s[6][64], o2s[6][64];
  float scl[4][6][6], a2l[4][6][6];
  float att0l[6], att1l[6], maskl[6];
  float redA[4], redC[4];
};

// ---- dataflow sync: PER-RING-SLOT split counters (exact; fixes r10's race) ----
// r10 bug: a single aggregate counter + producer run-ahead lets fast blocks'
// bumps for LATER steps falsely satisfy a wait for an EARLIER step (some slow
// producer not done -> consumer reads unwritten data; absmax ~1e3).
// Fix: one 8-line counter group PER RING SLOT (s = t mod 4). Group s only ever
// counts events for steps congruent to s; a producer cannot bump group s a
// second time until the consumer side of the previous occupancy has fully
// completed (gated by the opposite group), so targets are EXACT.
__device__ __forceinline__ void bump(unsigned* grp, int idx) {
  if (threadIdx.x == 0)
    __hip_atomic_fetch_add(grp + (idx & 7) * 32, 1u, __ATOMIC_RELEASE,
                           __HIP_MEMORY_SCOPE_AGENT);
}
template <int SLP>
__device__ __forceinline__ void waitSum(unsigned* grp, unsigned target) {
  if (threadIdx.x == 0) {
    for (;;) {
      unsigned s = 0;
#pragma unroll
      for (int i = 0; i < 8; ++i)
        s += __hip_atomic_load(grp + i * 32, __ATOMIC_ACQUIRE, __HIP_MEMORY_SCOPE_AGENT);
      if (s >= target) break;
      __builtin_amdgcn_s_sleep(SLP);
    }
  }
  __syncthreads();
}

__device__ __forceinline__ void block_sum2(float a, float c, float* redA, float* redC,
                                           int tid, float* outA, float* outC) {
  for (int off = 32; off; off >>= 1) {
    a += __shfl_down(a, off);
    c += __shfl_down(c, off);
  }
  if ((tid & 63) == 0) {
    redA[tid >> 6] = a;
    redC[tid >> 6] = c;
  }
  __syncthreads();
  *outA = redA[0] + redA[1] + redA[2] + redA[3];
  *outC = redC[0] + redC[1] + redC[2] + redC[3];
  __syncthreads();
}

// input-attention softmax for step tstep, batch b (fp32 end-to-end)
__device__ __forceinline__ void compute_att(const KParams& p, int b, int tstep, int tid,
                                            float (*hs)[256], float (*qv)[64],
                                            float* att0l, float* att1l) {
  for (int jj = tid; jj < 384; jj += 256) {
    int kb = jj >> 6, c = jj & 63;
    float acc = p.bq[c];
    const float4* wt = (const float4*)(p.wqT + (size_t)c * 256u);
    const float4* hv = (const float4*)(&hs[kb][0]);
    for (int j4 = 0; j4 < 64; ++j4) {
      float4 w = wt[j4], h4 = hv[j4];
      acc += h4.x * w.x;
      acc += h4.y * w.y;
      acc += h4.z * w.z;
      acc += h4.w * w.w;
    }
    qv[kb][c] = acc;
  }
  __syncthreads();
  if (tid < 64) {
    const float* kxr = p.kx + ((size_t)tstep * 64u + b) * 64u;
    float bkv = p.bk[tid], kxv = kxr[tid];
    for (int kb = 0; kb < 6; ++kb) {
      float q = qv[kb][tid];
      float p0 = q * bkv, p1 = q * kxv;
      for (int off = 32; off; off >>= 1) {
        p0 += __shfl_down(p0, off);
        p1 += __shfl_down(p1, off);
      }
      if (tid == 0) {
        float s0 = p0 * 0.125f, s1 = p1 * 0.125f;  // temperature sqrt(64)=8
        float mx = fmaxf(s0, s1);
        float e0 = expf(s0 - mx), e1 = expf(s1 - mx);
        float inv = 1.f / (e0 + e1);
        att0l[kb] = e0 * inv;
        att1l[kb] = e1 * inv;
      }
    }
  }
  __syncthreads();
}

__global__ __launch_bounds__(256) void rims_seq(KParams p) {
  const int bid = blockIdx.x, tid = threadIdx.x;
  const int wv_ = tid >> 6, lane = tid & 63;
  const int row = lane & 15, q8 = (lane >> 4) * 8;
  const int quad = lane >> 4, col = lane & 15;

  // Dynamic LDS (131072 B):
  // gi blocks: [0,65536) = wi_hi slice, [65536,131072) = wi_lo slice (32 cols x 1024 K)
  // B  blocks: [65536,...) = PhaseB scratch (~21.6 KB); [0,65536) unused
  extern __shared__ char smem[];

  const bool isGI = bid < 144;
  const int b = bid - 144;           // valid when !isGI (B block per batch)
  PhaseB& S = *reinterpret_cast<PhaseB*>(smem + 65536);

  // per-slot groups: giGrp[s] = bar + s*256, bGrp[s] = bar + 1024 + s*256
  unsigned* giGrpBase = p.bar;
  unsigned* bGrpBase = p.bar + 1024;

  // ---- gi blocks: stage wi slices into LDS (once; reused for all 256 steps).
  // XOR swizzle byte^=((col&7)<<4) breaks the K-stride row-major bank conflict (T2). ----
  if (isGI) {
    const int n0 = bid * 32;
#pragma unroll
    for (int pl = 0; pl < 2; ++pl) {
      const unsigned short* src = pl ? p.wi_lo : p.wi_hi;
      char* base = smem + pl * 65536;
      for (int idx = tid; idx < 4096; idx += 256) {  // 32 cols x 128 16B-chunks
        int c = idx >> 7, k8 = idx & 127;
        bf16x8 v = *(const bf16x8*)(src + ((size_t)(n0 + c) << 10) + (k8 << 3));
        int off = (c << 11) + (k8 << 4);
        off ^= (c & 7) << 4;
        *(bf16x8*)(base + off) = v;
      }
    }
  }
  // Order multi-wave LDS staging before ANY smem read (r5/r6 lesson).
  __syncthreads();

  if (isGI) {
    // ======== gi role: free-running 4-deep ring; independent of h entirely ========
    const int n0 = bid * 32;
    for (int t = 0; t < T_DIM; ++t) {
      // ring slot s=t&3 was last consumed (as step t-4) -> need bGrp[s] >= 64*(t>>2)
      if (t >= 4) waitSum<32>(bGrpBase + (t & 3) * 256, 64u * (unsigned)(t >> 2));
      const size_t aoff = ((size_t)t * 64u + wv_ * 16 + row) * 1024u + q8;
      f32x4 acc[2];
      acc[0] = (f32x4){0.f, 0.f, 0.f, 0.f};
      acc[1] = (f32x4){0.f, 0.f, 0.f, 0.f};
#pragma unroll 4
      for (int kk = 0; kk < 1024; kk += 32) {
        bf16x8 ah = *(const bf16x8*)(p.xv_hi + aoff + kk);   // plain: L2/L3-shared
        bf16x8 al = *(const bf16x8*)(p.xv_lo + aoff + kk);
#pragma unroll
        for (int nt = 0; nt < 2; ++nt) {
          int cl = nt * 16 + row;
          int off = (cl << 11) + ((kk + q8) << 1);
          off ^= (cl & 7) << 4;
          bf16x8 bh = *(const bf16x8*)(smem + off);
          bf16x8 bl = *(const bf16x8*)(smem + 65536 + off);
          acc[nt] = MFMA16(ah, bh, acc[nt]);
          acc[nt] = MFMA16(al, bh, acc[nt]);
          acc[nt] = MFMA16(ah, bl, acc[nt]);
        }
      }
      float* dst = p.gi_raw + (size_t)(t & 3) * GBUF;
#pragma unroll
      for (int nt = 0; nt < 2; ++nt)
#pragma unroll
        for (int r = 0; r < 4; ++r) {
          int m = wv_ * 16 + quad * 4 + r;
          CSTORE_F(&dst[(size_t)m * NCOL + n0 + nt * 16 + col], acc[nt][r]);
        }
      __syncthreads();  // drain stores before signaling
      bump(giGrpBase + (t & 3) * 256, bid);
    }
    return;
  }

  // ================== B role: one block per batch, everything local ==================
  // init: load h0 -> hs, att(0). No cross-block h publish -- h lives in LDS only.
  for (int kp = 0; kp < 6; ++kp)
    S.hs[kp][tid] = p.h_in[(size_t)b * 1536u + kp * 256 + tid];
  __syncthreads();
  compute_att(p, b, 0, tid, S.hs, S.qv, S.att0l, S.att1l);

  for (int t = 0; t < T_DIM; ++t) {
    // ---- local gh GEMV (exact fp32): gh[g,kp,j=tid] = sum_i hs[kp][i]*wh[g,kp,i,j].
    // wh row (i) contiguous across j -> lanes coalesce; wh (4.7MB) is read-only,
    // L2/L3-resident, no coherent path. 3 gates interleaved for FMA-latency ILP
    // (per-gate i-ascending FP order preserved).
    float ghv[18];
    for (int kp = 0; kp < 6; ++kp) {
      const float4* hv4 = (const float4*)(&S.hs[kp][0]);
      const float* W0 = p.wh + ((size_t)(0 * 6 + kp) << 16) + tid;
      const float* W1 = p.wh + ((size_t)(1 * 6 + kp) << 16) + tid;
      const float* W2 = p.wh + ((size_t)(2 * 6 + kp) << 16) + tid;
      float a0 = 0.f, a1 = 0.f, a2 = 0.f;
      for (int i4 = 0; i4 < 64; ++i4) {
        float4 h4 = hv4[i4];
        size_t r0 = (size_t)(i4 * 4 + 0) << 8;
        size_t r1 = (size_t)(i4 * 4 + 1) << 8;
        size_t r2 = (size_t)(i4 * 4 + 2) << 8;
        size_t r3 = (size_t)(i4 * 4 + 3) << 8;
        a0 += h4.x * W0[r0]; a1 += h4.x * W1[r0]; a2 += h4.x * W2[r0];
        a0 += h4.y * W0[r1]; a1 += h4.y * W1[r1]; a2 += h4.y * W2[r1];
        a0 += h4.z * W0[r2]; a1 += h4.z * W1[r2]; a2 += h4.z * W2[r2];
        a0 += h4.w * W0[r3]; a1 += h4.w * W1[r3]; a2 += h4.w * W2[r3];
      }
      ghv[kp * 3 + 0] = a0;
      ghv[kp * 3 + 1] = a1;
      ghv[kp * 3 + 2] = a2;
    }

    // ---- wait for gi(t): slot s=t&3 written (t>>2)+1 times ----
    waitSum<2>(giGrpBase + (t & 3) * 256, 144u * (unsigned)((t >> 2) + 1));

    if (tid < 6) {
      float my = S.att0l[tid];
      int cnt = 0;
      for (int k2 = 0; k2 < 6; ++k2)
        if (S.att0l[k2] > my || (S.att0l[k2] == my && k2 < tid)) cnt++;
      S.maskl[tid] = (cnt < 2) ? 0.f : 1.f;  // 2 largest-null blocks inactive
    }

    // coherent gi loads, issued up front (18 independent loads)
    const float* giB = p.gi_raw + (size_t)(t & 3) * GBUF;
    float giv[18];
#pragma unroll
    for (int kp = 0; kp < 6; ++kp)
#pragma unroll
      for (int g = 0; g < 3; ++g)
        giv[kp * 3 + g] = CLOAD_F(&giB[(size_t)b * NCOL + g * 1536 + kp * 256 + tid]);
    __syncthreads();  // loads complete (vmcnt drained) before consumption signal
    bump(bGrpBase + (t & 3) * 256, b);

    // GRU (gate order r,z,n) -- ghv is local now
    for (int kp = 0; kp < 6; ++kp) {
      float a1 = S.att1l[kp], a0 = S.att0l[kp];
      int ci = kp * 256 + tid;
      float gi0 = a1 * giv[kp * 3 + 0] + a0 * p.c0[ci] + p.bi[ci];
      float gi1 = a1 * giv[kp * 3 + 1] + a0 * p.c0[1536 + ci] + p.bi[1536 + ci];
      float gi2 = a1 * giv[kp * 3 + 2] + a0 * p.c0[3072 + ci] + p.bi[3072 + ci];
      float gh0 = ghv[kp * 3 + 0] + p.bh[ci];
      float gh1 = ghv[kp * 3 + 1] + p.bh[1536 + ci];
      float gh2 = ghv[kp * 3 + 2] + p.bh[3072 + ci];
      float r = sigm(gi0 + gh0);
      float z = sigm(gi1 + gh1);
      float n = tanhf(gi2 + r * gh2);
      S.hx[kp][tid] = (1.f - z) * n + z * S.hs[kp][tid];
    }
    __syncthreads();

    // q2/k2/v2 for all 6 blocks: 1152 dot-256 jobs (transposed W, float4 streams;
    // identical FP summation order: j sequential, single accumulator)
    for (int jj = tid; jj < 1152; jj += 256) {
      int type = jj / 384;
      int r = jj - type * 384;
      int kp = r >> 6, c = r & 63;
      const float* WT = (type == 0) ? p.cqT : (type == 1) ? p.ckT : p.cvT;
      float acc = ((type == 0) ? p.cbq : (type == 1) ? p.cbk : p.cbv)[c];
      const float4* wt = (const float4*)(WT + (size_t)c * 256u);
      const float4* hv = (const float4*)(&S.hx[kp][0]);
      for (int j4 = 0; j4 < 64; ++j4) {
        float4 w = wt[j4], h4 = hv[j4];
        acc += h4.x * w.x;
        acc += h4.y * w.y;
        acc += h4.z * w.z;
        acc += h4.w * w.w;
      }
      float* dst = (type == 0) ? &S.q2s[kp][c] : (type == 1) ? &S.k2s[kp][c] : &S.v2s[kp][c];
      *dst = acc;
    }
    __syncthreads();

    // scores (temperature sqrt(16)=4)
    if (tid < 144) {
      int hh = tid / 36, rem = tid % 36, qq = rem / 6, kk2 = rem % 6;
      float acc = 0.f;
      for (int d = 0; d < 16; ++d) acc += S.q2s[qq][hh * 16 + d] * S.k2s[kk2][hh * 16 + d];
      S.scl[hh][qq][kk2] = acc * 0.25f;
    }
    __syncthreads();
    if (tid < 24) {
      int hh = tid / 6, qq = tid % 6;
      float mx = -1e30f;
      for (int k2 = 0; k2 < 6; ++k2) mx = fmaxf(mx, S.scl[hh][qq][k2]);
      float s = 0.f;
      for (int k2 = 0; k2 < 6; ++k2) {
        float e = expf(S.scl[hh][qq][k2] - mx);
        S.a2l[hh][qq][k2] = e;
        s += e;
      }
      float inv = 1.f / s;
      for (int k2 = 0; k2 < 6; ++k2) S.a2l[hh][qq][k2] *= inv;
    }
    __syncthreads();
    for (int jj = tid; jj < 384; jj += 256) {
      int qq = jj >> 6, c = jj & 63, hh = c >> 4;
      float acc = 0.f;
      for (int k2 = 0; k2 < 6; ++k2) acc += S.a2l[hh][qq][k2] * S.v2s[k2][c];
      S.o2s[qq][c] = acc;
    }
    __syncthreads();

    // res = o2 @ cfc + cbfc + hx   (cfcT rows streamed as float4, same FP order)
    float rr[6];
    for (int kp = 0; kp < 6; ++kp) {
      float acc = p.cbfc[tid] + S.hx[kp][tid];
      const float4* ft = (const float4*)(p.cfcT + (size_t)tid * 64u);
      const float4* ov = (const float4*)(&S.o2s[kp][0]);
      for (int c4 = 0; c4 < 16; ++c4) {
        float4 f = ft[c4], o = ov[c4];
        acc += o.x * f.x;
        acc += o.y * f.y;
        acc += o.z * f.z;
        acc += o.w * f.w;
      }
      rr[kp] = acc;
    }
    __syncthreads();

    // LayerNorm + gated update (h stays local in LDS; no coherent publish)
    for (int kp = 0; kp < 6; ++kp) {
      float s, sq;
      block_sum2(rr[kp], rr[kp] * rr[kp], S.redA, S.redC, tid, &s, &sq);
      float mu = s * (1.f / 256.f);
      float var = sq * (1.f / 256.f) - mu * mu;
      float normed = (rr[kp] - mu) / sqrtf(var + 1e-5f);
      float hxf = S.hx[kp][tid] + normed * p.ln_g[tid] + p.ln_b[tid];
      float m = S.maskl[kp];
      float hn = m * hxf + (1.f - m) * S.hs[kp][tid];
      S.hs[kp][tid] = hn;
      size_t oidx = ((size_t)t * 64u + b) * 1536u + kp * 256 + tid;
      p.out[oidx] = hn;  // plain: flushed at kernel end
      if (t == T_DIM - 1) p.out[25165824u + (size_t)b * 1536u + kp * 256 + tid] = hn;
    }
    __syncthreads();

    if (t < T_DIM - 1) compute_att(p, b, t + 1, tid, S.hs, S.qv, S.att0l, S.att1l);
  }
}

// ================= host =================

extern "C" void kernel_launch(void* const* d_in, const int* in_sizes, int n_in, void* d_out,
                              int out_size, void* d_ws, size_t ws_size, hipStream_t stream) {
  (void)in_sizes; (void)n_in; (void)out_size; (void)ws_size;
  const float* inp = (const float*)d_in[0];
  const float* h_in = (const float*)d_in[1];
  const float* wq = (const float*)d_in[2];
  const float* bq = (const float*)d_in[3];
  const float* wk = (const float*)d_in[4];
  const float* bk = (const float*)d_in[5];
  const float* wv = (const float*)d_in[6];
  const float* bv = (const float*)d_in[7];
  const float* wi = (const float*)d_in[8];
  const float* wh = (const float*)d_in[9];
  const float* bi = (const float*)d_in[10];
  const float* bh = (const float*)d_in[11];
  const float* cq = (const float*)d_in[12];
  const float* cbq = (const float*)d_in[13];
  const float* ck = (const float*)d_in[14];
  const float* cbk = (const float*)d_in[15];
  const float* cv = (const float*)d_in[16];
  const float* cbv = (const float*)d_in[17];
  const float* cfc = (const float*)d_in[18];
  const float* cbfc = (const float*)d_in[19];
  const float* ln_g = (const float*)d_in[20];
  const float* ln_b = (const float*)d_in[21];

  // Workspace layout kept UNDER the proven-safe bound (~104 MB from passing rounds).
  // gi_raw (4-deep ring, used only by rims_seq) aliases the wv hi/lo planes
  // (dead after xv_gemm): 4*1,179,648 = 4,718,592 <= 6,291,456.
  char* ws = (char*)d_ws;
  const size_t o_wv_hi = 0;            // 3,145,728
  const size_t o_wv_lo = 3145728;      // 3,145,728
  const size_t o_wi_hi = 6291456;      // 9,437,184
  const size_t o_wi_lo = 15728640;     // 9,437,184
  const size_t o_wh_hi = 25165824;     // 2,359,296 (written, unused by local-gh design)
  const size_t o_wh_lo = 27525120;     // 2,359,296 (written, unused)
  const size_t o_xv_hi = 29884416;     // 33,554,432
  const size_t o_xv_lo = 63438848;     // 33,554,432
  const size_t o_kx = 96993280;        // 4,194,304
  const size_t o_c0 = 101187584;       // 18,432
  const size_t o_bar = 101206016;      // 8,192 (2 groups x 4 slots x 8 lines x 128 B)
  const size_t o_cqT = 101214208;      // 65,536
  const size_t o_ckT = 101279744;      // 65,536
  const size_t o_cvT = 101345280;      // 65,536
  const size_t o_wqT = 101410816;      // 65,536
  const size_t o_cfcT = 101476352;     // 65,536  (end 101,541,888 < proven 103,959,552)

  unsigned short* wv_hi = (unsigned short*)(ws + o_wv_hi);
  unsigned short* wv_lo = (unsigned short*)(ws + o_wv_lo);
  unsigned short* wi_hi = (unsigned short*)(ws + o_wi_hi);
  unsigned short* wi_lo = (unsigned short*)(ws + o_wi_lo);
  unsigned short* wh_hi = (unsigned short*)(ws + o_wh_hi);
  unsigned short* wh_lo = (unsigned short*)(ws + o_wh_lo);
  unsigned short* xv_hi = (unsigned short*)(ws + o_xv_hi);
  unsigned short* xv_lo = (unsigned short*)(ws + o_xv_lo);
  float* kx = (float*)(ws + o_kx);
  float* c0 = (float*)(ws + o_c0);

  hipMemsetAsync(ws + o_bar, 0, 8192, stream);
  convert_weights<<<2048, 256, 0, stream>>>(wv, wi, wh, wv_hi, wv_lo, wi_hi, wi_lo, wh_hi, wh_lo);
  transpose_small<<<128, 256, 0, stream>>>(cq, ck, cv, wq, cfc,
                                           (float*)(ws + o_cqT), (float*)(ws + o_ckT),
                                           (float*)(ws + o_cvT), (float*)(ws + o_wqT),
                                           (float*)(ws + o_cfcT));
  kx_kernel<<<1024, 256, 0, stream>>>(inp, wk, bk, kx);
  xv_gemm<<<dim3(8, 128), 256, 0, stream>>>(inp, wv_hi, wv_lo, bv, xv_hi, xv_lo);
  c0_kernel<<<18, 256, 0, stream>>>(bv, wi, c0);

  KParams prm;
  prm.h_in = h_in; prm.wq = wq; prm.bq = bq; prm.bk = bk;
  prm.bi = bi; prm.bh = bh; prm.wh = wh;
  prm.cq = cq; prm.cbq = cbq; prm.ck = ck; prm.cbk = cbk;
  prm.cv = cv; prm.cbv = cbv; prm.cfc = cfc; prm.cbfc = cbfc;
  prm.ln_g = ln_g; prm.ln_b = ln_b;
  prm.cqT = (const float*)(ws + o_cqT);
  prm.ckT = (const float*)(ws + o_ckT);
  prm.cvT = (const float*)(ws + o_cvT);
  prm.wqT = (const float*)(ws + o_wqT);
  prm.cfcT = (const float*)(ws + o_cfcT);
  prm.xv_hi = xv_hi; prm.xv_lo = xv_lo;
  prm.wi_hi = wi_hi; prm.wi_lo = wi_lo;
  prm.kx = kx; prm.c0 = c0;
  prm.gi_raw = (float*)(ws + o_wv_hi);   // 4-deep ring, aliases wv planes
  prm.bar = (unsigned*)(ws + o_bar);
  prm.out = (float*)d_out;

  // raise the dynamic-LDS cap (static __shared__ is limited to 64 KiB; gi blocks
  // need 128 KiB -> 1 block/CU, 208 blocks co-resident on 256 CUs)
  hipFuncSetAttribute(reinterpret_cast<const void*>(&rims_seq),
                      hipFuncAttributeMaxDynamicSharedMemorySize, 131072);
  rims_seq<<<GRID_N, 256, 131072, stream>>>(prm);
}

// Round 12
// 40329.907 us; speedup vs baseline: 5.8101x; 5.8101x over previous
//
#include <hip/hip_runtime.h>

// ---- problem dims ----
#define T_DIM 256
#define NCOL 4608   // 3 gates * NB * BS  (col index n = g*1536 + k*256 + h)
// persistent grid: 144 gi blocks (32 cols each, wi hi+lo slices in LDS)
//                 + 72 gh blocks (64 cols each, wh hi+lo slices in LDS); gh[0..63] also host Phase B
#define GRID_N 216
#define GBUF 294912u   // floats per gi_raw/gh_raw buffer (64*4608); double-buffered

typedef __bf16 bf16x8 __attribute__((ext_vector_type(8)));
typedef float f32x4 __attribute__((ext_vector_type(4)));

#define MFMA16(a, b, c) __builtin_amdgcn_mfma_f32_16x16x32_bf16((a), (b), (c), 0, 0, 0)

#define CLOAD_F(ptr) __hip_atomic_load((ptr), __ATOMIC_RELAXED, __HIP_MEMORY_SCOPE_AGENT)
#define CSTORE_F(ptr, v) __hip_atomic_store((ptr), (v), __ATOMIC_RELAXED, __HIP_MEMORY_SCOPE_AGENT)

__device__ __forceinline__ unsigned short f2bf(float f) {
  unsigned u = __float_as_uint(f);
  unsigned r = u + 0x7FFFu + ((u >> 16) & 1u);
  return (unsigned short)(r >> 16);
}
__device__ __forceinline__ float bf2f(unsigned short s) {
  return __uint_as_float(((unsigned)s) << 16);
}
// split-bf16: x ~= hi + lo with |x - hi - lo| <= 2^-18 |x|
__device__ __forceinline__ void split2(float f, unsigned short* hi, unsigned short* lo) {
  unsigned short h = f2bf(f);
  *hi = h;
  *lo = f2bf(f - bf2f(h));
}

__device__ __forceinline__ void pack8_split(const float* p, bf16x8* hi, bf16x8* lo) {
  union { unsigned short s[8]; bf16x8 v; } uh, ul;
#pragma unroll
  for (int i = 0; i < 8; ++i) split2(p[i], &uh.s[i], &ul.s[i]);
  *hi = uh.v;
  *lo = ul.v;
}

__device__ __forceinline__ float sigm(float x) { return 1.f / (1.f + expf(-x)); }

// ================= precompute kernels =================

// weight transposes to split-bf16 hi/lo planes (K-contiguous rows for MFMA B-frags)
__global__ void convert_weights(const float* __restrict__ wv, const float* __restrict__ wi,
                                const float* __restrict__ wh,
                                unsigned short* __restrict__ wv_hi, unsigned short* __restrict__ wv_lo,
                                unsigned short* __restrict__ wi_hi, unsigned short* __restrict__ wi_lo,
                                unsigned short* __restrict__ wh_hi, unsigned short* __restrict__ wh_lo) {
  const size_t N0 = 1024u * 1536u;
  const size_t N1 = 18u * 256u * 1024u;
  const size_t N2 = 18u * 256u * 256u;
  for (size_t idx = blockIdx.x * 256u + threadIdx.x; idx < N0 + N1 + N2;
       idx += (size_t)gridDim.x * 256u) {
    if (idx < N0) {
      size_t n = idx / 1536u, kk = idx % 1536u;
      split2(wv[kk * 1024u + n], &wv_hi[idx], &wv_lo[idx]);
    } else if (idx < N0 + N1) {
      size_t r = idx - N0;
      size_t gk = r / 262144u, rem = r % 262144u;
      size_t h = rem / 1024u, kk = rem % 1024u;
      split2(wi[gk * 262144u + kk * 256u + h], &wi_hi[r], &wi_lo[r]);
    } else {
      size_t r = idx - N0 - N1;
      size_t gk = r / 65536u, rem = r % 65536u;
      size_t nout = rem / 256u, kin = rem % 256u;
      split2(wh[gk * 65536u + kin * 256u + nout], &wh_hi[r], &wh_lo[r]);
    }
  }
}

// fp32 transposes of the small comm-attn weights (vector-load-friendly rows);
// FP summation order in consumers is unchanged (j stays sequential).
__global__ void transpose_small(const float* __restrict__ cq, const float* __restrict__ ck,
                                const float* __restrict__ cv, const float* __restrict__ wq,
                                const float* __restrict__ cfc,
                                float* __restrict__ cqT, float* __restrict__ ckT,
                                float* __restrict__ cvT, float* __restrict__ wqT,
                                float* __restrict__ cfcT) {
  int i = blockIdx.x * 256 + threadIdx.x;
  if (i < 16384) {            // [256][64] -> [64][256]
    int r = i >> 6, c = i & 63;
    cqT[c * 256 + r] = cq[i];
    ckT[c * 256 + r] = ck[i];
    cvT[c * 256 + r] = cv[i];
    wqT[c * 256 + r] = wq[i];
  } else if (i < 32768) {     // cfc [64][256] -> [256][64]
    int j = i - 16384;
    int r = j >> 8, c = j & 255;
    cfcT[c * 64 + r] = cfc[j];
  }
}

// kx[t*64+b][64] = x @ wk + bk  -- exact fp32 (feeds discrete top-k decisions)
__global__ void kx_kernel(const float* __restrict__ x, const float* __restrict__ wk,
                          const float* __restrict__ bk, float* __restrict__ kx) {
  __shared__ float xs[16][64];
  const int mb = blockIdx.x;
  const int tid = threadIdx.x;
  const int mi = tid >> 6, n = tid & 63;
  float acc[4] = {0.f, 0.f, 0.f, 0.f};
  for (int kk0 = 0; kk0 < 1536; kk0 += 64) {
    __syncthreads();
    for (int i = tid; i < 1024; i += 256) {
      int r = i >> 6, c = i & 63;
      xs[r][c] = x[(size_t)(mb * 16 + r) * 1536u + kk0 + c];
    }
    __syncthreads();
    for (int c = 0; c < 64; ++c) {
      float w = wk[(size_t)(kk0 + c) * 64u + n];
      acc[0] += xs[mi][c] * w;
      acc[1] += xs[mi + 4][c] * w;
      acc[2] += xs[mi + 8][c] * w;
      acc[3] += xs[mi + 12][c] * w;
    }
  }
  for (int i = 0; i < 4; ++i)
    kx[(size_t)(mb * 16 + mi + 4 * i) * 64u + n] = acc[i] + bk[n];
}

// xv = x @ wv + bv via split-bf16 MFMA (3-term), output stored as hi/lo planes
__global__ __launch_bounds__(256) void xv_gemm(const float* __restrict__ x,
                                               const unsigned short* __restrict__ wv_hi,
                                               const unsigned short* __restrict__ wv_lo,
                                               const float* __restrict__ bv,
                                               unsigned short* __restrict__ xv_hi,
                                               unsigned short* __restrict__ xv_lo) {
  const int nb = blockIdx.x, mb = blockIdx.y;  // 8 x 128
  const int tid = threadIdx.x;
  const int w = tid >> 6, lane = tid & 63;
  const int mh = w >> 1, nh = w & 1;
  const int row = lane & 15, q8 = (lane >> 4) * 8;
  const int m0 = mb * 128 + mh * 64;
  const int n0 = nb * 128 + nh * 64;
  f32x4 acc[4][4];
#pragma unroll
  for (int i = 0; i < 4; ++i)
#pragma unroll
    for (int j = 0; j < 4; ++j) acc[i][j] = (f32x4){0.f, 0.f, 0.f, 0.f};
  for (int kk = 0; kk < 1536; kk += 32) {
    bf16x8 ah[4], al[4], bh[4], bl[4];
#pragma unroll
    for (int mt = 0; mt < 4; ++mt)
      pack8_split(x + (size_t)(m0 + mt * 16 + row) * 1536u + kk + q8, &ah[mt], &al[mt]);
#pragma unroll
    for (int nt = 0; nt < 4; ++nt) {
      size_t off = (size_t)(n0 + nt * 16 + row) * 1536u + kk + q8;
      bh[nt] = *(const bf16x8*)(wv_hi + off);
      bl[nt] = *(const bf16x8*)(wv_lo + off);
    }
#pragma unroll
    for (int mt = 0; mt < 4; ++mt)
#pragma unroll
      for (int nt = 0; nt < 4; ++nt) {
        acc[mt][nt] = MFMA16(ah[mt], bh[nt], acc[mt][nt]);
        acc[mt][nt] = MFMA16(al[mt], bh[nt], acc[mt][nt]);
        acc[mt][nt] = MFMA16(ah[mt], bl[nt], acc[mt][nt]);
      }
  }
  const int quad = lane >> 4, col = lane & 15;
#pragma unroll
  for (int mt = 0; mt < 4; ++mt)
#pragma unroll
    for (int nt = 0; nt < 4; ++nt)
#pragma unroll
      for (int r = 0; r < 4; ++r) {
        int m = m0 + mt * 16 + quad * 4 + r;
        int n = n0 + nt * 16 + col;
        split2(acc[mt][nt][r] + bv[n], &xv_hi[(size_t)m * 1024u + n],
               &xv_lo[(size_t)m * 1024u + n]);
      }
}

// c0[gk][h] = bv @ wi[gk]   (null-slot value path; exact fp32)
__global__ void c0_kernel(const float* __restrict__ bv, const float* __restrict__ wi,
                          float* __restrict__ c0) {
  const int gk = blockIdx.x, h = threadIdx.x;
  const float* wp = wi + (size_t)gk * 262144u + h;
  float acc = 0.f;
  for (int kk = 0; kk < 1024; ++kk) acc += bv[kk] * wp[(size_t)kk * 256u];
  c0[gk * 256 + h] = acc;
}

// ================= persistent kernel =================

struct KParams {
  const float *h_in, *wq, *bq, *bk;
  const float *bi, *bh;
  const float *cq, *cbq, *ck, *cbk, *cv, *cbv, *cfc, *cbfc, *ln_g, *ln_b;
  const float *cqT, *ckT, *cvT, *wqT, *cfcT;
  const unsigned short *xv_hi, *xv_lo, *wi_hi, *wi_lo, *wh_hi, *wh_lo;
  const float *kx, *c0;
  float *gi_raw, *gh_raw;     // double-buffered (parity t&1), device-coherent
  unsigned* h_pack;           // (hi<<16)|lo packed split-bf16 h; device-coherent
  unsigned* bar;              // counter groups + epoch lines (see kernel)
  float* out;
};

// Phase-B scratch, at smem+65536 above the gh blocks' wh slices; cfc LDS copy
// (64 KB, c-major = original cfc layout) sits above it at smem+87040.
struct PhaseB {
  float hs[6][256], hx[6][256];
  float qv[6][64];
  float q2s[6][64], k2s[6][64], v2s[6][64], o2s[6][64];
  float scl[4][6][6], a2l[4][6][6];
  float att0l[6], att1l[6], maskl[6];
  float redA[4], redC[4];
};

// ---- dataflow sync: split RMW counters + EPOCH broadcast ----
// r8 measured ~205us/step with ~5us work; 216 blocks polling the RMW lines is
// the prime suspect. Fix: only 2 aggregator blocks poll RMW lines (tight);
// everyone else polls read-only epoch words (pure release store / acquire load).
// giGrp is PER-RING-SLOT (2 slots) -- closes r8's latent skew race (r11-proven).
__device__ __forceinline__ void bump(unsigned* grp, int idx) {
  if (threadIdx.x == 0)
    __hip_atomic_fetch_add(grp + (idx & 7) * 32, 1u, __ATOMIC_RELEASE,
                           __HIP_MEMORY_SCOPE_AGENT);
}
template <int SLP>
__device__ __forceinline__ void waitSum(unsigned* grp, unsigned target) {
  if (threadIdx.x == 0) {
    for (;;) {
      unsigned s = 0;
#pragma unroll
      for (int i = 0; i < 8; ++i)
        s += __hip_atomic_load(grp + i * 32, __ATOMIC_ACQUIRE, __HIP_MEMORY_SCOPE_AGENT);
      if (s >= target) break;
      __builtin_amdgcn_s_sleep(SLP);
    }
  }
  __syncthreads();
}
__device__ __forceinline__ void pubEp(unsigned* ep, unsigned v) {
  __hip_atomic_store(ep, v, __ATOMIC_RELEASE, __HIP_MEMORY_SCOPE_AGENT);
}
template <int SLP>
__device__ __forceinline__ void waitEp(unsigned* ep, unsigned target) {
  if (threadIdx.x == 0) {
    while (__hip_atomic_load(ep, __ATOMIC_ACQUIRE, __HIP_MEMORY_SCOPE_AGENT) < target)
      __builtin_amdgcn_s_sleep(SLP);
  }
  __syncthreads();
}

__device__ __forceinline__ void block_sum2(float a, float c, float* redA, float* redC,
                                           int tid, float* outA, float* outC) {
  for (int off = 32; off; off >>= 1) {
    a += __shfl_down(a, off);
    c += __shfl_down(c, off);
  }
  if ((tid & 63) == 0) {
    redA[tid >> 6] = a;
    redC[tid >> 6] = c;
  }
  __syncthreads();
  *outA = redA[0] + redA[1] + redA[2] + redA[3];
  *outC = redC[0] + redC[1] + redC[2] + redC[3];
  __syncthreads();
}

// input-attention softmax for step tstep, batch b (fp32 end-to-end; summation
// order identical to prior verified kernel -- wqT only vectorizes the loads)
__device__ __forceinline__ void compute_att(const KParams& p, int b, int tstep, int tid,
                                            float (*hs)[256], float (*qv)[64],
                                            float* att0l, float* att1l) {
  for (int jj = tid; jj < 384; jj += 256) {
    int kb = jj >> 6, c = jj & 63;
    float acc = p.bq[c];
    const float4* wt = (const float4*)(p.wqT + (size_t)c * 256u);
    const float4* hv = (const float4*)(&hs[kb][0]);
    for (int j4 = 0; j4 < 64; ++j4) {
      float4 w = wt[j4], h4 = hv[j4];
      acc += h4.x * w.x;
      acc += h4.y * w.y;
      acc += h4.z * w.z;
      acc += h4.w * w.w;
    }
    qv[kb][c] = acc;
  }
  __syncthreads();
  if (tid < 64) {
    const float* kxr = p.kx + ((size_t)tstep * 64u + b) * 64u;
    float bkv = p.bk[tid], kxv = kxr[tid];
    for (int kb = 0; kb < 6; ++kb) {
      float q = qv[kb][tid];
      float p0 = q * bkv, p1 = q * kxv;
      for (int off = 32; off; off >>= 1) {
        p0 += __shfl_down(p0, off);
        p1 += __shfl_down(p1, off);
      }
      if (tid == 0) {
        float s0 = p0 * 0.125f, s1 = p1 * 0.125f;  // temperature sqrt(64)=8
        float mx = fmaxf(s0, s1);
        float e0 = expf(s0 - mx), e1 = expf(s1 - mx);
        float inv = 1.f / (e0 + e1);
        att0l[kb] = e0 * inv;
        att1l[kb] = e1 * inv;
      }
    }
  }
  __syncthreads();
}

__global__ __launch_bounds__(256) void rims_seq(KParams p) {
  const int bid = blockIdx.x, tid = threadIdx.x;
  const int wv_ = tid >> 6, lane = tid & 63;
  const int row = lane & 15, q8 = (lane >> 4) * 8;
  const int quad = lane >> 4, col = lane & 15;

  // Dynamic LDS (152576 B):
  // gi blocks: [0,65536) = wi_hi slice, [65536,131072) = wi_lo slice
  // gh blocks: [0,32768) = wh_hi slice, [32768,65536) = wh_lo slice,
  //            [65536,86760) = PhaseB, [87040,152576) = cfc LDS copy (B hosts)
  extern __shared__ char smem[];

  const bool isGI = bid < 144;
  const int gh_id = bid - 144;             // valid when !isGI
  const bool isB = (!isGI) && gh_id < 64;  // Phase-B host
  const int b = gh_id;
  PhaseB& S = *reinterpret_cast<PhaseB*>(smem + 65536);
  float* cfcLds = (float*)(smem + 87040);

  unsigned* hGrp = p.bar;          // B-block completions (64/gen; init = gen 1) [exact]
  unsigned* ghGrp = p.bar + 256;   // gh-block completions (72/step) [exact]
  unsigned* giS0 = p.bar + 512;    // gi completions, ring slot 0 (steps 0,2,4..)
  unsigned* giS1 = p.bar + 768;    // gi completions, ring slot 1 (steps 1,3,5..)
  unsigned* hEp = p.bar + 1024;    // epoch: h generation available
  unsigned* bgEp = p.bar + 1032;   // epoch: B(t) may start

  // ---- stage this block's weight slices into LDS (once; reused for all 256 steps).
  // XOR swizzle byte^=((col&7)<<4) breaks the K-stride row-major bank conflict (T2). ----
  if (isGI) {
    const int n0 = bid * 32;
#pragma unroll
    for (int pl = 0; pl < 2; ++pl) {
      const unsigned short* src = pl ? p.wi_lo : p.wi_hi;
      char* base = smem + pl * 65536;
      for (int idx = tid; idx < 4096; idx += 256) {  // 32 cols x 128 16B-chunks
        int c = idx >> 7, k8 = idx & 127;
        bf16x8 v = *(const bf16x8*)(src + ((size_t)(n0 + c) << 10) + (k8 << 3));
        int off = (c << 11) + (k8 << 4);
        off ^= (c & 7) << 4;
        *(bf16x8*)(base + off) = v;
      }
    }
  } else {
    const int gk = gh_id >> 2, q4 = gh_id & 3;
    const size_t wbase = (size_t)gk * 65536u + (size_t)(q4 * 64) * 256u;
#pragma unroll
    for (int pl = 0; pl < 2; ++pl) {
      const unsigned short* src = pl ? p.wh_lo : p.wh_hi;
      char* base = smem + pl * 32768;
      for (int idx = tid; idx < 2048; idx += 256) {  // 64 cols x 32 16B-chunks
        int c = idx >> 5, k8 = idx & 31;
        bf16x8 v = *(const bf16x8*)(src + wbase + (size_t)c * 256u + (k8 << 3));
        int off = (c << 9) + (k8 << 4);
        off ^= (c & 7) << 4;
        *(bf16x8*)(base + off) = v;
      }
    }
    if (isB) {
      // stage cfc (c-major original layout) -- coalesced copy, conflict-free reads
      for (int i = tid; i < 16384; i += 256) cfcLds[i] = p.cfc[i];
    }
  }
  // CRITICAL: order multi-wave LDS staging before ANY smem read (r5/r6 lesson).
  __syncthreads();

  // ---- init: B hosts load h0, publish packed copy, bump hGrp (gen 1), att(0) ----
  if (isB) {
    for (int kp = 0; kp < 6; ++kp) {
      float h0 = p.h_in[(size_t)b * 1536u + kp * 256 + tid];
      S.hs[kp][tid] = h0;
      unsigned short hhi, hlo;
      split2(h0, &hhi, &hlo);
      CSTORE_F(&p.h_pack[(size_t)b * 1536u + kp * 256 + tid], ((unsigned)hhi << 16) | hlo);
    }
    __syncthreads();  // drain h_pack stores
    bump(hGrp, b);
    compute_att(p, b, 0, tid, S.hs, S.qv, S.att0l, S.att1l);
  }

  if (isGI) {
    // =================== gi role: free-running, up to 2 steps ahead ===================
    const int n0 = bid * 32;
    for (int t = 0; t < T_DIM; ++t) {
      // buffer gi_raw[t&1] is free once B(t-2) has consumed it: hEp >= t
      if (t >= 2) waitEp<32>(hEp, (unsigned)t);
      const size_t aoff = ((size_t)t * 64u + wv_ * 16 + row) * 1024u + q8;
      f32x4 acc[2];
      acc[0] = (f32x4){0.f, 0.f, 0.f, 0.f};
      acc[1] = (f32x4){0.f, 0.f, 0.f, 0.f};
#pragma unroll 4
      for (int kk = 0; kk < 1024; kk += 32) {
        bf16x8 ah = *(const bf16x8*)(p.xv_hi + aoff + kk);   // plain: L2/L3-shared
        bf16x8 al = *(const bf16x8*)(p.xv_lo + aoff + kk);
#pragma unroll
        for (int nt = 0; nt < 2; ++nt) {
          int cl = nt * 16 + row;
          int off = (cl << 11) + ((kk + q8) << 1);
          off ^= (cl & 7) << 4;
          bf16x8 bh = *(const bf16x8*)(smem + off);
          bf16x8 bl = *(const bf16x8*)(smem + 65536 + off);
          acc[nt] = MFMA16(ah, bh, acc[nt]);
          acc[nt] = MFMA16(al, bh, acc[nt]);
          acc[nt] = MFMA16(ah, bl, acc[nt]);
        }
      }
      float* dst = p.gi_raw + (size_t)(t & 1) * GBUF;
#pragma unroll
      for (int nt = 0; nt < 2; ++nt)
#pragma unroll
        for (int r = 0; r < 4; ++r) {
          int m = wv_ * 16 + quad * 4 + r;
          CSTORE_F(&dst[(size_t)m * NCOL + n0 + nt * 16 + col], acc[nt][r]);
        }
      __syncthreads();  // drain stores before signaling
      bump((t & 1) ? giS1 : giS0, bid);
    }
    return;
  }

  // =================== gh role (+ Phase-B host for gh_id < 64) ===================
  const int gk = gh_id >> 2, q4 = gh_id & 3;
  const int kbb = gk % 6;
  const int n0gh = (gk / 6) * 1536 + kbb * 256 + q4 * 64;
  const bool isAggH = (gh_id == 64);   // aggregates hGrp -> hEp
  const bool isAggB = (gh_id == 65);   // aggregates giS*,ghGrp -> bgEp

  for (int t = 0; t < T_DIM; ++t) {
    // ---- gh(t): needs h generation t+1 (published by B(t-1) / init) ----
    if (isAggH) {
      waitSum<2>(hGrp, 64u * (unsigned)(t + 1));
      if (tid == 0) pubEp(hEp, (unsigned)(t + 1));
    } else {
      waitEp<4>(hEp, (unsigned)(t + 1));
    }
    {
      const unsigned long long* hp64 =
          (const unsigned long long*)(p.h_pack + (size_t)(wv_ * 16 + row) * 1536u + kbb * 256 + q8);
      f32x4 acc[4];
#pragma unroll
      for (int nt = 0; nt < 4; ++nt) acc[nt] = (f32x4){0.f, 0.f, 0.f, 0.f};
#pragma unroll
      for (int half = 0; half < 2; ++half) {
        // coherent h loads as 64-bit atomics, 16 issued up front for this half
        unsigned long long u8[16];
#pragma unroll
        for (int i = 0; i < 16; ++i) {
          int g = i >> 2, e2 = i & 3;
          u8[i] = __hip_atomic_load(hp64 + half * 64 + g * 16 + e2, __ATOMIC_RELAXED,
                                    __HIP_MEMORY_SCOPE_AGENT);
        }
#pragma unroll
        for (int i = 0; i < 4; ++i) {
          union { unsigned short s[8]; bf16x8 v; } hh, llo;
#pragma unroll
          for (int e = 0; e < 4; ++e) {
            unsigned long long w2 = u8[i * 4 + e];
            unsigned d0 = (unsigned)w2, d1 = (unsigned)(w2 >> 32);
            hh.s[e * 2 + 0] = (unsigned short)(d0 >> 16);
            llo.s[e * 2 + 0] = (unsigned short)d0;
            hh.s[e * 2 + 1] = (unsigned short)(d1 >> 16);
            llo.s[e * 2 + 1] = (unsigned short)d1;
          }
          const int kloc = half * 128 + i * 32;
#pragma unroll
          for (int nt = 0; nt < 4; ++nt) {
            int cl = nt * 16 + row;
            int off = (cl << 9) + ((kloc + q8) << 1);
            off ^= (cl & 7) << 4;
            bf16x8 bh = *(const bf16x8*)(smem + off);
            bf16x8 bl = *(const bf16x8*)(smem + 32768 + off);
            acc[nt] = MFMA16(hh.v, bh, acc[nt]);
            acc[nt] = MFMA16(llo.v, bh, acc[nt]);
            acc[nt] = MFMA16(hh.v, bl, acc[nt]);
          }
        }
      }
      float* dst = p.gh_raw + (size_t)(t & 1) * GBUF;
#pragma unroll
      for (int nt = 0; nt < 4; ++nt)
#pragma unroll
        for (int r = 0; r < 4; ++r) {
          int m = wv_ * 16 + quad * 4 + r;
          CSTORE_F(&dst[(size_t)m * NCOL + n0gh + nt * 16 + col], acc[nt][r]);
        }
    }
    __syncthreads();  // drain stores before signaling
    bump(ghGrp, gh_id);

    // ---- bgEp aggregator: publish "B(t) may start" once gi(t)+gh(t) complete ----
    if (isAggB) {
      waitSum<2>((t & 1) ? giS1 : giS0, 144u * (unsigned)((t >> 1) + 1));
      waitSum<2>(ghGrp, 72u * (unsigned)(t + 1));
      if (tid == 0) pubEp(bgEp, (unsigned)(t + 1));
    }

    // ---- Phase B(t): one block per batch ----
    if (isB) {
      waitEp<4>(bgEp, (unsigned)(t + 1));

      if (tid < 6) {
        float my = S.att0l[tid];
        int cnt = 0;
        for (int k2 = 0; k2 < 6; ++k2)
          if (S.att0l[k2] > my || (S.att0l[k2] == my && k2 < tid)) cnt++;
        S.maskl[tid] = (cnt < 2) ? 0.f : 1.f;  // 2 largest-null blocks inactive
      }

      // coherent GRU inputs, issued up front (36 independent loads)
      const float* giB = p.gi_raw + (size_t)(t & 1) * GBUF;
      const float* ghB = p.gh_raw + (size_t)(t & 1) * GBUF;
      float giv[18], ghv[18];
#pragma unroll
      for (int kp = 0; kp < 6; ++kp)
#pragma unroll
        for (int g = 0; g < 3; ++g) {
          size_t base = (size_t)b * NCOL + g * 1536 + kp * 256 + tid;
          giv[kp * 3 + g] = CLOAD_F(&giB[base]);
          ghv[kp * 3 + g] = CLOAD_F(&ghB[base]);
        }
      __syncthreads();

      // GRU (gate order r,z,n)
      for (int kp = 0; kp < 6; ++kp) {
        float a1 = S.att1l[kp], a0 = S.att0l[kp];
        int ci = kp * 256 + tid;
        float gi0 = a1 * giv[kp * 3 + 0] + a0 * p.c0[ci] + p.bi[ci];
        float gi1 = a1 * giv[kp * 3 + 1] + a0 * p.c0[1536 + ci] + p.bi[1536 + ci];
        float gi2 = a1 * giv[kp * 3 + 2] + a0 * p.c0[3072 + ci] + p.bi[3072 + ci];
        float gh0 = ghv[kp * 3 + 0] + p.bh[ci];
        float gh1 = ghv[kp * 3 + 1] + p.bh[1536 + ci];
        float gh2 = ghv[kp * 3 + 2] + p.bh[3072 + ci];
        float r = sigm(gi0 + gh0);
        float z = sigm(gi1 + gh1);
        float n = tanhf(gi2 + r * gh2);
        S.hx[kp][tid] = (1.f - z) * n + z * S.hs[kp][tid];
      }
      __syncthreads();

      // q2/k2/v2 for all 6 blocks: 1152 dot-256 jobs (transposed W, float4 streams;
      // identical FP summation order: j sequential, single accumulator)
      for (int jj = tid; jj < 1152; jj += 256) {
        int type = jj / 384;
        int r = jj - type * 384;
        int kp = r >> 6, c = r & 63;
        const float* WT = (type == 0) ? p.cqT : (type == 1) ? p.ckT : p.cvT;
        float acc = ((type == 0) ? p.cbq : (type == 1) ? p.cbk : p.cbv)[c];
        const float4* wt = (const float4*)(WT + (size_t)c * 256u);
        const float4* hv = (const float4*)(&S.hx[kp][0]);
        for (int j4 = 0; j4 < 64; ++j4) {
          float4 w = wt[j4], h4 = hv[j4];
          acc += h4.x * w.x;
          acc += h4.y * w.y;
          acc += h4.z * w.z;
          acc += h4.w * w.w;
        }
        float* dst = (type == 0) ? &S.q2s[kp][c] : (type == 1) ? &S.k2s[kp][c] : &S.v2s[kp][c];
        *dst = acc;
      }
      __syncthreads();

      // scores (temperature sqrt(16)=4)
      if (tid < 144) {
        int hh = tid / 36, rem = tid % 36, qq = rem / 6, kk2 = rem % 6;
        float acc = 0.f;
        for (int d = 0; d < 16; ++d) acc += S.q2s[qq][hh * 16 + d] * S.k2s[kk2][hh * 16 + d];
        S.scl[hh][qq][kk2] = acc * 0.25f;
      }
      __syncthreads();
      if (tid < 24) {
        int hh = tid / 6, qq = tid % 6;
        float mx = -1e30f;
        for (int k2 = 0; k2 < 6; ++k2) mx = fmaxf(mx, S.scl[hh][qq][k2]);
        float s = 0.f;
        for (int k2 = 0; k2 < 6; ++k2) {
          float e = expf(S.scl[hh][qq][k2] - mx);
          S.a2l[hh][qq][k2] = e;
          s += e;
        }
        float inv = 1.f / s;
        for (int k2 = 0; k2 < 6; ++k2) S.a2l[hh][qq][k2] *= inv;
      }
      __syncthreads();
      for (int jj = tid; jj < 384; jj += 256) {
        int qq = jj >> 6, c = jj & 63, hh = c >> 4;
        float acc = 0.f;
        for (int k2 = 0; k2 < 6; ++k2) acc += S.a2l[hh][qq][k2] * S.v2s[k2][c];
        S.o2s[qq][c] = acc;
      }
      __syncthreads();

      // res = o2 @ cfc + cbfc + hx  (cfc from LDS, c-major: conflict-free, same FP order)
      float rr[6];
      for (int kp = 0; kp < 6; ++kp) {
        float acc = p.cbfc[tid] + S.hx[kp][tid];
        for (int c = 0; c < 64; ++c) acc += S.o2s[kp][c] * cfcLds[c * 256 + tid];
        rr[kp] = acc;
      }
      __syncthreads();

      // LayerNorm + gated update
      for (int kp = 0; kp < 6; ++kp) {
        float s, sq;
        block_sum2(rr[kp], rr[kp] * rr[kp], S.redA, S.redC, tid, &s, &sq);
        float mu = s * (1.f / 256.f);
        float var = sq * (1.f / 256.f) - mu * mu;
        float normed = (rr[kp] - mu) / sqrtf(var + 1e-5f);
        float hxf = S.hx[kp][tid] + normed * p.ln_g[tid] + p.ln_b[tid];
        float m = S.maskl[kp];
        float hn = m * hxf + (1.f - m) * S.hs[kp][tid];
        S.hs[kp][tid] = hn;
        size_t oidx = ((size_t)t * 64u + b) * 1536u + kp * 256 + tid;
        p.out[oidx] = hn;  // plain: flushed at kernel end
        if (t == T_DIM - 1) p.out[25165824u + (size_t)b * 1536u + kp * 256 + tid] = hn;
        unsigned short hhi, hlo;
        split2(hn, &hhi, &hlo);
        CSTORE_F(&p.h_pack[(size_t)b * 1536u + kp * 256 + tid], ((unsigned)hhi << 16) | hlo);
      }
      __syncthreads();  // drain h_pack stores before signaling next generation
      bump(hGrp, b);

      if (t < T_DIM - 1) compute_att(p, b, t + 1, tid, S.hs, S.qv, S.att0l, S.att1l);
    }
  }
}

// ================= host =================

extern "C" void kernel_launch(void* const* d_in, const int* in_sizes, int n_in, void* d_out,
                              int out_size, void* d_ws, size_t ws_size, hipStream_t stream) {
  (void)in_sizes; (void)n_in; (void)out_size; (void)ws_size;
  const float* inp = (const float*)d_in[0];
  const float* h_in = (const float*)d_in[1];
  const float* wq = (const float*)d_in[2];
  const float* bq = (const float*)d_in[3];
  const float* wk = (const float*)d_in[4];
  const float* bk = (const float*)d_in[5];
  const float* wv = (const float*)d_in[6];
  const float* bv = (const float*)d_in[7];
  const float* wi = (const float*)d_in[8];
  const float* wh = (const float*)d_in[9];
  const float* bi = (const float*)d_in[10];
  const float* bh = (const float*)d_in[11];
  const float* cq = (const float*)d_in[12];
  const float* cbq = (const float*)d_in[13];
  const float* ck = (const float*)d_in[14];
  const float* cbk = (const float*)d_in[15];
  const float* cv = (const float*)d_in[16];
  const float* cbv = (const float*)d_in[17];
  const float* cfc = (const float*)d_in[18];
  const float* cbfc = (const float*)d_in[19];
  const float* ln_g = (const float*)d_in[20];
  const float* ln_b = (const float*)d_in[21];

  // Workspace layout kept UNDER the proven-safe bound (~104 MB from passing rounds).
  // gi_raw/gh_raw (used only by rims_seq) alias the wv hi/lo planes (dead after xv_gemm).
  char* ws = (char*)d_ws;
  const size_t o_wv_hi = 0;            // 3,145,728  (later: gi_raw 2,359,296)
  const size_t o_wv_lo = 3145728;      // 3,145,728  (later: gh_raw 2,359,296)
  const size_t o_wi_hi = 6291456;      // 9,437,184
  const size_t o_wi_lo = 15728640;     // 9,437,184
  const size_t o_wh_hi = 25165824;     // 2,359,296
  const size_t o_wh_lo = 27525120;     // 2,359,296
  const size_t o_xv_hi = 29884416;     // 33,554,432
  const size_t o_xv_lo = 63438848;     // 33,554,432
  const size_t o_kx = 96993280;        // 4,194,304
  const size_t o_c0 = 101187584;       // 18,432
  const size_t o_hpack = 101206016;    // 393,216
  const size_t o_bar = 101599232;      // 8,192 (4 RMW groups + epoch lines)
  const size_t o_cqT = 101607424;      // 65,536
  const size_t o_ckT = 101672960;      // 65,536
  const size_t o_cvT = 101738496;      // 65,536
  const size_t o_wqT = 101804032;      // 65,536
  const size_t o_cfcT = 101869568;     // 65,536  (end 101,935,104 < proven 103,959,552)

  unsigned short* wv_hi = (unsigned short*)(ws + o_wv_hi);
  unsigned short* wv_lo = (unsigned short*)(ws + o_wv_lo);
  unsigned short* wi_hi = (unsigned short*)(ws + o_wi_hi);
  unsigned short* wi_lo = (unsigned short*)(ws + o_wi_lo);
  unsigned short* wh_hi = (unsigned short*)(ws + o_wh_hi);
  unsigned short* wh_lo = (unsigned short*)(ws + o_wh_lo);
  unsigned short* xv_hi = (unsigned short*)(ws + o_xv_hi);
  unsigned short* xv_lo = (unsigned short*)(ws + o_xv_lo);
  float* kx = (float*)(ws + o_kx);
  float* c0 = (float*)(ws + o_c0);

  hipMemsetAsync(ws + o_bar, 0, 8192, stream);
  convert_weights<<<2048, 256, 0, stream>>>(wv, wi, wh, wv_hi, wv_lo, wi_hi, wi_lo, wh_hi, wh_lo);
  transpose_small<<<128, 256, 0, stream>>>(cq, ck, cv, wq, cfc,
                                           (float*)(ws + o_cqT), (float*)(ws + o_ckT),
                                           (float*)(ws + o_cvT), (float*)(ws + o_wqT),
                                           (float*)(ws + o_cfcT));
  kx_kernel<<<1024, 256, 0, stream>>>(inp, wk, bk, kx);
  xv_gemm<<<dim3(8, 128), 256, 0, stream>>>(inp, wv_hi, wv_lo, bv, xv_hi, xv_lo);
  c0_kernel<<<18, 256, 0, stream>>>(bv, wi, c0);

  KParams prm;
  prm.h_in = h_in; prm.wq = wq; prm.bq = bq; prm.bk = bk;
  prm.bi = bi; prm.bh = bh;
  prm.cq = cq; prm.cbq = cbq; prm.ck = ck; prm.cbk = cbk;
  prm.cv = cv; prm.cbv = cbv; prm.cfc = cfc; prm.cbfc = cbfc;
  prm.ln_g = ln_g; prm.ln_b = ln_b;
  prm.cqT = (const float*)(ws + o_cqT);
  prm.ckT = (const float*)(ws + o_ckT);
  prm.cvT = (const float*)(ws + o_cvT);
  prm.wqT = (const float*)(ws + o_wqT);
  prm.cfcT = (const float*)(ws + o_cfcT);
  prm.xv_hi = xv_hi; prm.xv_lo = xv_lo;
  prm.wi_hi = wi_hi; prm.wi_lo = wi_lo;
  prm.wh_hi = wh_hi; prm.wh_lo = wh_lo;
  prm.kx = kx; prm.c0 = c0;
  prm.gi_raw = (float*)(ws + o_wv_hi);   // aliases wv_hi (dead after xv_gemm)
  prm.gh_raw = (float*)(ws + o_wv_lo);   // aliases wv_lo (dead after xv_gemm)
  prm.h_pack = (unsigned*)(ws + o_hpack);
  prm.bar = (unsigned*)(ws + o_bar);
  prm.out = (float*)d_out;

  // raise the dynamic-LDS cap: 152,576 B/block (gi: 128K wi; gh: 64K wh + PhaseB +
  // 64K cfc LDS copy for B hosts) -> 1 block/CU, 216 blocks co-resident on 256 CUs
  hipFuncSetAttribute(reinterpret_cast<const void*>(&rims_seq),
                      hipFuncAttributeMaxDynamicSharedMemorySize, 152576);
  rims_seq<<<GRID_N, 256, 152576, stream>>>(prm);
}